// Round 11
// baseline (339.244 us; speedup 1.0000x reference)
//
#include <hip/hip_runtime.h>
#include <math.h>

#define NFEAT 256
#define NROWS 65536
#define PCOUNT 4194304
#define PBLK 64                      // param-reduce blocks appended to pass1 grid
#define CH2 512                      // pass2 fallback chunks
#define RGRP 8                       // reduce_S c-groups
#define F_EPS 5.9604645e-07f         // float32 eps * 5
#define F_LN2 0.69314718056f
#define DELTA_MAX 0.45f              // poly-validity gate on |0.1*rp|

#define FAST_LOG2(v) __builtin_log2f(v)   // v_log_f32
#define FAST_EXP2(v) __builtin_exp2f(v)   // v_exp_f32

constexpr double D_HALF_LOG2_2PIE = 0.5 * 2.8378770664093453 / 0.6931471805599453;
constexpr double D_LAMBDA_BITS = 13.287712379549449; // 2*log2(100)

__device__ inline double wave_reduce_add(double v) {
  for (int o = 32; o > 0; o >>= 1) v += __shfl_down(v, o, 64);
  return v;
}

// ---------------------------------------------------------------------------
// Pass 1: 512-thread blocks: (f = tid&255, sub = tid>>8). Block c covers rows
// [c*64,(c+1)*64); sub halves the rows. Each thread: all 6 proposals.
// Poly path: 1 log + 1 exp per element; exp2(a_j*u) = B * poly(delta_j)
// where B = exp2(center*u), poly = 1 + d*q + (dq)^2/2 + ... + (dq)^5/120,
// q = u*ln2. Gated by precheck (no lambda special cases, |delta|<=0.45).
// Partials: P1[(c*14+k)*NFEAT+f]; k 0..5 sum_y, 6..11 sum_y2,
// 12 sum_u2(pos), 13 sum_u2(all); u2 = log2(1+|x|).
// Blocks >= CHv: parameter tensor reduction (overlapped, memory-bound).
// ---------------------------------------------------------------------------
__global__ __launch_bounds__(512, 8) void k_pass1(
    const float* __restrict__ x, const float* __restrict__ lam1,
    const float* __restrict__ lam2, const float* __restrict__ rp,
    const float* __restrict__ params, float* __restrict__ P1,
    double* __restrict__ pSums, int CHv, int rpt)
{
  const int c = blockIdx.x;
  const int tid = threadIdx.x;

  if (c >= CHv) {
    // ---- parameter tensor partial reduction ----
    __shared__ double lred[2][8];
    const int b = c - CHv;
    const float4* p4 = (const float4*)params;
    double s = 0.0, q = 0.0;
    for (int i = b * 512 + tid; i < PCOUNT / 4; i += PBLK * 512) {
      float4 v = p4[i];
      s += (double)v.x + (double)v.y + (double)v.z + (double)v.w;
      q += (double)v.x * v.x + (double)v.y * v.y
         + (double)v.z * v.z + (double)v.w * v.w;
    }
    s = wave_reduce_add(s); q = wave_reduce_add(q);
    const int w = tid >> 6;
    if ((tid & 63) == 0) { lred[0][w] = s; lred[1][w] = q; }
    __syncthreads();
    if (tid == 0) {
      double S = 0.0, Q = 0.0;
#pragma unroll
      for (int i = 0; i < 8; ++i) { S += lred[0][i]; Q += lred[1][i]; }
      atomicAdd(&pSums[0], S);
      atomicAdd(&pSums[1], Q);
    }
    return;
  }

  const int f = tid & 255;
  const int sub = tid >> 8;            // 0/1: row half
  const int rps = rpt >> 1;            // rows per sub
  __shared__ int bad;
  __shared__ float red[14][NFEAT];
  if (tid == 0) bad = 0;
  __syncthreads();

  const float L1 = lam1[f], L2 = lam2[f];
  const float An = 2.0f - L2;          // negative-branch center
  float d_p[6], d_n[6], s_p[6], s_n[6];
  bool b = false;
#pragma unroll
  for (int j = 0; j < 6; ++j) {
    float dp = (j == 0) ? 0.0f : 0.1f * rp[f * 10 + 2 * (j - 1)];
    float dn = (j == 0) ? 0.0f : -0.1f * rp[f * 10 + 2 * (j - 1) + 1];
    d_p[j] = dp;  d_n[j] = dn;
    float a1 = L1 + dp;                // l1_j
    float a2 = An + dn;                // 2 - l2_j
    s_p[j] = 1.0f / a1;
    s_n[j] = -1.0f / a2;
    b = b || (fabsf(a1) < F_EPS) || (fabsf(a2) < F_EPS)
          || (fabsf(dp) > DELTA_MAX) || (fabsf(dn) > DELTA_MAX);
  }
  if (b) bad = 1;  // benign same-value race
  __syncthreads();

  float as[6], aq[6];
#pragma unroll
  for (int j = 0; j < 6; ++j) { as[j] = 0.f; aq[j] = 0.f; }
  float u2p = 0.f, u2a = 0.f;
  const float* xp = x + ((size_t)c * rpt + sub * rps) * NFEAT + f;

  if (bad == 0) {
    // ---- poly path: 1 log + 1 exp per element ----
    for (int i = 0; i < rps; i += 4) {
      float v4[4];
#pragma unroll
      for (int r = 0; r < 4; ++r) v4[r] = xp[(size_t)(i + r) * NFEAT];
#pragma unroll
      for (int r = 0; r < 4; ++r) {
        const float v = v4[r];
        const bool pos = v >= 0.0f;
        const float u = FAST_LOG2(1.0f + fabsf(v));
        u2a += u;
        u2p += pos ? u : 0.0f;
        const float q = u * F_LN2;
        const float B = FAST_EXP2((pos ? L1 : An) * u);
        const float m2 = 0.5f * (q * q);
        const float m3 = m2 * q * 0.333333333f;
        const float m4 = m3 * q * 0.25f;
        const float m5 = m4 * q * 0.2f;
#pragma unroll
        for (int j = 0; j < 6; ++j) {
          const float d = pos ? d_p[j] : d_n[j];
          const float s = pos ? s_p[j] : s_n[j];
          float P = m5;
          P = fmaf(P, d, m4);
          P = fmaf(P, d, m3);
          P = fmaf(P, d, m2);
          P = fmaf(P, d, q);
          P = fmaf(P, d, 1.0f);
          const float E = B * P;           // exp2(a_j * u)
          const float y = fmaf(s, E, -s);  // s*(E-1)
          as[j] += y;
          aq[j] = fmaf(y, y, aq[j]);
        }
      }
    }
  } else {
    // ---- exact general path (lambda special cases / large delta) ----
    float ga_p[6], ga_n[6], gs_p[6], gs_n[6], gt_p[6], gt_n[6];
#pragma unroll
    for (int j = 0; j < 6; ++j) {
      float a1 = L1 + d_p[j];
      float a2 = An + d_n[j];
      bool z1 = fabsf(a1) < F_EPS;
      bool z2 = fabsf(a2) < F_EPS;
      ga_p[j] = z1 ? 0.0f : a1;
      gs_p[j] = z1 ? 0.0f : 1.0f / a1;
      gt_p[j] = z1 ? F_LN2 : 0.0f;
      ga_n[j] = z2 ? 0.0f : a2;
      gs_n[j] = z2 ? 0.0f : -1.0f / a2;
      gt_n[j] = z2 ? -F_LN2 : 0.0f;
    }
    for (int i = 0; i < rps; ++i) {
      float v = xp[(size_t)i * NFEAT];
      bool pos = v >= 0.0f;
      float u2 = FAST_LOG2(1.0f + fabsf(v));
      u2a += u2;
      u2p += pos ? u2 : 0.0f;
#pragma unroll
      for (int j = 0; j < 6; ++j) {
        float a  = pos ? ga_p[j] : ga_n[j];
        float s  = pos ? gs_p[j] : gs_n[j];
        float tt = pos ? gt_p[j] : gt_n[j];
        float e = FAST_EXP2(a * u2);
        float y = fmaf(tt, u2, fmaf(s, e, -s));
        as[j] += y;
        aq[j] = fmaf(y, y, aq[j]);
      }
    }
  }

  // merge the two row-subs via LDS; sub0 stores
  if (sub == 1) {
#pragma unroll
    for (int j = 0; j < 6; ++j) { red[j][f] = as[j]; red[6 + j][f] = aq[j]; }
    red[12][f] = u2p; red[13][f] = u2a;
  }
  __syncthreads();
  if (sub == 0) {
#pragma unroll
    for (int j = 0; j < 6; ++j) {
      P1[((size_t)c * 14 + j) * NFEAT + f]     = as[j] + red[j][f];
      P1[((size_t)c * 14 + 6 + j) * NFEAT + f] = aq[j] + red[6 + j][f];
    }
    P1[((size_t)c * 14 + 12) * NFEAT + f] = u2p + red[12][f];
    P1[((size_t)c * 14 + 13) * NFEAT + f] = u2a + red[13][f];
  }
}

// Stage A reduce: block (k, cg): S2[(k*RGRP+cg)*NFEAT+f] = sum over c-subrange.
__global__ __launch_bounds__(256) void k_reduce_S(
    const float* __restrict__ P1, double* __restrict__ S2, int CHv)
{
  const int k = blockIdx.x / RGRP;
  const int cg = blockIdx.x % RGRP;
  const int f = threadIdx.x;
  const int per = CHv / RGRP;
  const int c0 = cg * per;
  double a0 = 0.0, a1 = 0.0, a2 = 0.0, a3 = 0.0;
  for (int c = c0; c < c0 + per; c += 4) {
    a0 += (double)P1[((size_t)(c + 0) * 14 + k) * NFEAT + f];
    a1 += (double)P1[((size_t)(c + 1) * 14 + k) * NFEAT + f];
    a2 += (double)P1[((size_t)(c + 2) * 14 + k) * NFEAT + f];
    a3 += (double)P1[((size_t)(c + 3) * 14 + k) * NFEAT + f];
  }
  S2[((size_t)k * RGRP + cg) * NFEAT + f] = (a0 + a1) + (a2 + a3);
}

// One thread per feature: 6 scores in f64, min, tie-average.
__global__ __launch_bounds__(256) void k_pick(
    const double* __restrict__ S2, const float* __restrict__ lam1,
    const float* __restrict__ lam2, const float* __restrict__ rp,
    float* __restrict__ bestL, int* __restrict__ tied,
    double* __restrict__ bitsF, int* __restrict__ anyTied)
{
  const int f = threadIdx.x;
  if (f == 0) *anyTied = 0;
  double s[14];
#pragma unroll
  for (int k = 0; k < 14; ++k) {
    double a = 0.0;
#pragma unroll
    for (int cg = 0; cg < RGRP; ++cg)
      a += S2[((size_t)k * RGRP + cg) * NFEAT + f];
    s[k] = a;
  }
  const double n = (double)NROWS;
  const double sup = s[12];
  const double sun = s[13] - s[12];
  const float L1 = lam1[f], L2 = lam2[f];
  double scores[6], al1[6], al2[6];
#pragma unroll
  for (int j = 0; j < 6; ++j) {
    float l1 = (j == 0) ? L1 : L1 + 0.1f * rp[f * 10 + 2 * (j - 1)];
    float l2 = (j == 0) ? L2 : L2 + 0.1f * rp[f * 10 + 2 * (j - 1) + 1];
    al1[j] = (double)l1; al2[j] = (double)l2;
    bool z1 = fabsf(l1) < F_EPS;
    bool z2 = fabsf(l2 - 2.0f) < F_EPS;
    double ccp = z1 ? -1.0 : (double)l1 - 1.0;
    double ccn = z2 ? -1.0 : 1.0 - (double)l2;
    double ljb = ccp * sup + ccn * sun;
    double mean = s[j] / n;
    double var = s[6 + j] / n - mean * mean;
    var = var > 1e-12 ? var : 1e-12;
    scores[j] = n * (D_HALF_LOG2_2PIE + 0.5 * log2(var)) + ljb + D_LAMBDA_BITS;
  }
  double mn = scores[0];
#pragma unroll
  for (int j = 1; j < 6; ++j) mn = scores[j] < mn ? scores[j] : mn;
  double wsum = 0.0, b1 = 0.0, b2 = 0.0;
#pragma unroll
  for (int j = 0; j < 6; ++j) {
    double w = (scores[j] == mn) ? 1.0 : 0.0;
    wsum += w; b1 += w * al1[j]; b2 += w * al2[j];
  }
  bestL[2 * f]     = (float)(b1 / wsum);
  bestL[2 * f + 1] = (float)(b2 / wsum);
  const int isTied = (wsum > 1.5) ? 1 : 0;
  tied[f] = isTied;
  if (isTied) atomicOr(anyTied, 1);
  bitsF[f] = mn;   // unique min: identical to re-evaluating at best lambda
}

// Fallback pass 2 (only if some feature tied: averaged lambda is new).
__global__ __launch_bounds__(256) void k_pass2(
    const float* __restrict__ x, const float* __restrict__ bestL,
    const int* __restrict__ anyTied, float* __restrict__ P2)
{
  if (*anyTied == 0) return;
  const int t = threadIdx.x;
  const int c = blockIdx.x;
  const int rpt = NROWS / CH2;   // 128
  const float l1 = bestL[2 * t], l2 = bestL[2 * t + 1];
  const bool z1 = fabsf(l1) < F_EPS;
  const bool z2 = fabsf(l2 - 2.0f) < F_EPS;
  const float tm = 2.0f - l2;
  const float a_p = z1 ? 0.f : l1,  s_pv = z1 ? 0.f : 1.f / l1,  t_pv = z1 ? F_LN2 : 0.f;
  const float a_n = z2 ? 0.f : tm,  s_nv = z2 ? 0.f : -1.f / tm, t_nv = z2 ? -F_LN2 : 0.f;

  float sy = 0.f, sq = 0.f;
  const float* xp = x + (size_t)c * rpt * NFEAT + t;
  for (int i = 0; i < rpt; ++i) {
    float v = xp[(size_t)i * NFEAT];
    bool pos = v >= 0.0f;
    float u2 = FAST_LOG2(1.0f + fabsf(v));
    float a  = pos ? a_p : a_n;
    float s  = pos ? s_pv : s_nv;
    float tt = pos ? t_pv : t_nv;
    float e = FAST_EXP2(a * u2);
    float y = fmaf(tt, u2, fmaf(s, e, -s));
    sy += y;
    sq = fmaf(y, y, sq);
  }
  P2[((size_t)c * 2 + 0) * NFEAT + t] = sy;
  P2[((size_t)c * 2 + 1) * NFEAT + t] = sq;
}

__global__ __launch_bounds__(64) void k_featbits(
    const float* __restrict__ P1, const float* __restrict__ P2,
    const float* __restrict__ bestL, const int* __restrict__ tied,
    double* __restrict__ bitsF, int CHv)
{
  const int f = blockIdx.x;
  if (!tied[f]) return;
  const int lane = threadIdx.x;
  double s0 = 0.0, s1 = 0.0, sup = 0.0, sua = 0.0;
  for (int c = lane; c < CH2; c += 64) {
    s0 += (double)P2[((size_t)c * 2 + 0) * NFEAT + f];
    s1 += (double)P2[((size_t)c * 2 + 1) * NFEAT + f];
  }
  for (int c = lane; c < CHv; c += 64) {
    sup += (double)P1[((size_t)c * 14 + 12) * NFEAT + f];
    sua += (double)P1[((size_t)c * 14 + 13) * NFEAT + f];
  }
  s0 = wave_reduce_add(s0); s1 = wave_reduce_add(s1);
  sup = wave_reduce_add(sup); sua = wave_reduce_add(sua);
  if (lane == 0) {
    const float l1 = bestL[2 * f], l2 = bestL[2 * f + 1];
    bool z1 = fabsf(l1) < F_EPS;
    bool z2 = fabsf(l2 - 2.0f) < F_EPS;
    double ccp = z1 ? -1.0 : (double)l1 - 1.0;
    double ccn = z2 ? -1.0 : 1.0 - (double)l2;
    double ljb = ccp * sup + ccn * (sua - sup);
    const double n = (double)NROWS;
    double mean = s0 / n;
    double var = s1 / n - mean * mean;
    var = var > 1e-12 ? var : 1e-12;
    bitsF[f] = n * (D_HALF_LOG2_2PIE + 0.5 * log2(var)) + ljb + D_LAMBDA_BITS;
  }
}

__global__ __launch_bounds__(256) void k_final(
    const double* __restrict__ bitsF, const double* __restrict__ pSums,
    float* __restrict__ out)
{
  __shared__ double l[4];
  double s = bitsF[threadIdx.x];
  s = wave_reduce_add(s);
  int w = threadIdx.x >> 6;
  if ((threadIdx.x & 63) == 0) l[w] = s;
  __syncthreads();
  if (threadIdx.x == 0) {
    double data = l[0] + l[1] + l[2] + l[3];
    const double n = (double)PCOUNT;
    double mean = pSums[0] / n;
    double var = pSums[1] / n - mean * mean;
    var = var > 1e-12 ? var : 1e-12;
    double model = n * (D_HALF_LOG2_2PIE + 0.5 * log2(var)) + D_LAMBDA_BITS;
    out[0] = (float)(data + model);
  }
}

extern "C" void kernel_launch(void* const* d_in, const int* in_sizes, int n_in,
                              void* d_out, int out_size, void* d_ws, size_t ws_size,
                              hipStream_t stream)
{
  const float* x      = (const float*)d_in[0];
  const float* lam1   = (const float*)d_in[1];
  const float* lam2   = (const float*)d_in[2];
  const float* rp     = (const float*)d_in[3];
  const float* params = (const float*)d_in[4];

  char* ws = (char*)d_ws;
  double* pSums  = (double*)ws;                 // 16 B   -> 16
  float*  bestL  = (float*)(ws + 16);           // 2048   -> 2064
  double* bitsF  = (double*)(ws + 2064);        // 2048   -> 4112
  int*    tied   = (int*)(ws + 4112);           // 1024   -> 5136
  int*    anyT   = (int*)(ws + 5136);           // 4      -> pad 5152
  double* S2     = (double*)(ws + 5152);        // 14*8*256*8 = 229376 -> 234528
  float*  P1     = (float*)(ws + 234528);

  // adaptive chunk count: prefer CH=1024 (4 blocks/CU of 512 threads)
  int CHv = 1024;
  while (CHv > 256) {
    size_t need = 234528 + (size_t)CHv * 14 * NFEAT * 4
                         + (size_t)CH2 * 2 * NFEAT * 4;
    if (need <= ws_size) break;
    CHv >>= 1;
  }
  float* P2 = (float*)(ws + 234528 + (size_t)CHv * 14 * NFEAT * 4);
  int rpt = NROWS / CHv;

  (void)hipMemsetAsync(pSums, 0, 16, stream);
  k_pass1<<<CHv + PBLK, 512, 0, stream>>>(x, lam1, lam2, rp, params, P1,
                                          pSums, CHv, rpt);
  k_reduce_S<<<14 * RGRP, 256, 0, stream>>>(P1, S2, CHv);
  k_pick<<<1, 256, 0, stream>>>(S2, lam1, lam2, rp, bestL, tied, bitsF, anyT);
  k_pass2<<<CH2, 256, 0, stream>>>(x, bestL, anyT, P2);
  k_featbits<<<NFEAT, 64, 0, stream>>>(P1, P2, bestL, tied, bitsF, CHv);
  k_final<<<1, 256, 0, stream>>>(bitsF, pSums, (float*)d_out);
}

// Round 12
// 77.015 us; speedup vs baseline: 4.4049x; 4.4049x over previous
//
#include <hip/hip_runtime.h>
#include <math.h>

#define NFEAT 256
#define NROWS 65536
#define PCOUNT 4194304
#define PBLK 64                      // param-reduce blocks appended to pass1 grid
#define CH2 512                      // pass2 fallback chunks
#define RGRP 8                       // reduce_S c-groups
#define F_EPS 5.9604645e-07f         // float32 eps * 5
#define F_LN2 0.69314718056f
#define DELTA_MAX 0.45f              // poly-validity gate on |0.1*rp|

#define FAST_LOG2(v) __builtin_log2f(v)   // v_log_f32
#define FAST_EXP2(v) __builtin_exp2f(v)   // v_exp_f32

constexpr double D_HALF_LOG2_2PIE = 0.5 * 2.8378770664093453 / 0.6931471805599453;
constexpr double D_LAMBDA_BITS = 13.287712379549449; // 2*log2(100)

__device__ inline double wave_reduce_add(double v) {
  for (int o = 32; o > 0; o >>= 1) v += __shfl_down(v, o, 64);
  return v;
}

// ---------------------------------------------------------------------------
// Pass 1: 512-thread blocks: (f = tid&255, sub = tid>>8). Block c covers rows
// [c*rpt,(c+1)*rpt); sub halves the rows. Each thread: all 6 proposals.
// Poly path: 1 log + 1 exp per element; exp2(a_j*u) = B * poly(delta_j)
// where B = exp2(center*u), poly = 1 + d*q + ... + (dq)^5/120, q = u*ln2.
// Gated by precheck (no lambda special cases, |delta|<=0.45).
// launch_bounds (512,4): 128-VGPR budget -- poly live set ~80 regs, NO spill
// (r11's (512,8)=64-reg cap spilled 780 MB and ran 8x slower).
// Partials: P1[(c*14+k)*NFEAT+f]; k 0..5 sum_y, 6..11 sum_y2,
// 12 sum_u2(pos), 13 sum_u2(all); u2 = log2(1+|x|).
// Blocks >= CHv: parameter tensor reduction (overlapped, memory-bound).
// ---------------------------------------------------------------------------
__global__ __launch_bounds__(512, 4) void k_pass1(
    const float* __restrict__ x, const float* __restrict__ lam1,
    const float* __restrict__ lam2, const float* __restrict__ rp,
    const float* __restrict__ params, float* __restrict__ P1,
    double* __restrict__ pSums, int CHv, int rpt)
{
  const int c = blockIdx.x;
  const int tid = threadIdx.x;

  if (c >= CHv) {
    // ---- parameter tensor partial reduction ----
    __shared__ double lred[2][8];
    const int b = c - CHv;
    const float4* p4 = (const float4*)params;
    double s = 0.0, q = 0.0;
    for (int i = b * 512 + tid; i < PCOUNT / 4; i += PBLK * 512) {
      float4 v = p4[i];
      s += (double)v.x + (double)v.y + (double)v.z + (double)v.w;
      q += (double)v.x * v.x + (double)v.y * v.y
         + (double)v.z * v.z + (double)v.w * v.w;
    }
    s = wave_reduce_add(s); q = wave_reduce_add(q);
    const int w = tid >> 6;
    if ((tid & 63) == 0) { lred[0][w] = s; lred[1][w] = q; }
    __syncthreads();
    if (tid == 0) {
      double S = 0.0, Q = 0.0;
#pragma unroll
      for (int i = 0; i < 8; ++i) { S += lred[0][i]; Q += lred[1][i]; }
      atomicAdd(&pSums[0], S);
      atomicAdd(&pSums[1], Q);
    }
    return;
  }

  const int f = tid & 255;
  const int sub = tid >> 8;            // 0/1: row half
  const int rps = rpt >> 1;            // rows per sub
  __shared__ int bad;
  __shared__ float red[14][NFEAT];
  if (tid == 0) bad = 0;
  __syncthreads();

  const float L1 = lam1[f], L2 = lam2[f];
  const float An = 2.0f - L2;          // negative-branch center
  float d_p[6], d_n[6], s_p[6], s_n[6];
  bool b = false;
#pragma unroll
  for (int j = 0; j < 6; ++j) {
    float dp = (j == 0) ? 0.0f : 0.1f * rp[f * 10 + 2 * (j - 1)];
    float dn = (j == 0) ? 0.0f : -0.1f * rp[f * 10 + 2 * (j - 1) + 1];
    d_p[j] = dp;  d_n[j] = dn;
    float a1 = L1 + dp;                // l1_j
    float a2 = An + dn;                // 2 - l2_j
    s_p[j] = 1.0f / a1;
    s_n[j] = -1.0f / a2;
    b = b || (fabsf(a1) < F_EPS) || (fabsf(a2) < F_EPS)
          || (fabsf(dp) > DELTA_MAX) || (fabsf(dn) > DELTA_MAX);
  }
  if (b) bad = 1;  // benign same-value race
  __syncthreads();

  float as[6], aq[6];
#pragma unroll
  for (int j = 0; j < 6; ++j) { as[j] = 0.f; aq[j] = 0.f; }
  float u2p = 0.f, u2a = 0.f;
  const float* xp = x + ((size_t)c * rpt + sub * rps) * NFEAT + f;

  if (bad == 0) {
    // ---- poly path: 1 log + 1 exp per element ----
    for (int i = 0; i < rps; i += 2) {
      float v2[2];
#pragma unroll
      for (int r = 0; r < 2; ++r) v2[r] = xp[(size_t)(i + r) * NFEAT];
#pragma unroll
      for (int r = 0; r < 2; ++r) {
        const float v = v2[r];
        const bool pos = v >= 0.0f;
        const float u = FAST_LOG2(1.0f + fabsf(v));
        u2a += u;
        u2p += pos ? u : 0.0f;
        const float q = u * F_LN2;
        const float B = FAST_EXP2((pos ? L1 : An) * u);
        const float m2 = 0.5f * (q * q);
        const float m3 = m2 * q * 0.333333333f;
        const float m4 = m3 * q * 0.25f;
        const float m5 = m4 * q * 0.2f;
#pragma unroll
        for (int j = 0; j < 6; ++j) {
          const float d = pos ? d_p[j] : d_n[j];
          const float s = pos ? s_p[j] : s_n[j];
          float P = m5;
          P = fmaf(P, d, m4);
          P = fmaf(P, d, m3);
          P = fmaf(P, d, m2);
          P = fmaf(P, d, q);
          P = fmaf(P, d, 1.0f);
          const float E = B * P;           // exp2(a_j * u)
          const float y = fmaf(s, E, -s);  // s*(E-1)
          as[j] += y;
          aq[j] = fmaf(y, y, aq[j]);
        }
      }
    }
  } else {
    // ---- exact general path (lambda special cases / large delta) ----
    float ga_p[6], ga_n[6], gs_p[6], gs_n[6], gt_p[6], gt_n[6];
#pragma unroll
    for (int j = 0; j < 6; ++j) {
      float a1 = L1 + d_p[j];
      float a2 = An + d_n[j];
      bool z1 = fabsf(a1) < F_EPS;
      bool z2 = fabsf(a2) < F_EPS;
      ga_p[j] = z1 ? 0.0f : a1;
      gs_p[j] = z1 ? 0.0f : 1.0f / a1;
      gt_p[j] = z1 ? F_LN2 : 0.0f;
      ga_n[j] = z2 ? 0.0f : a2;
      gs_n[j] = z2 ? 0.0f : -1.0f / a2;
      gt_n[j] = z2 ? -F_LN2 : 0.0f;
    }
    for (int i = 0; i < rps; ++i) {
      float v = xp[(size_t)i * NFEAT];
      bool pos = v >= 0.0f;
      float u2 = FAST_LOG2(1.0f + fabsf(v));
      u2a += u2;
      u2p += pos ? u2 : 0.0f;
#pragma unroll
      for (int j = 0; j < 6; ++j) {
        float a  = pos ? ga_p[j] : ga_n[j];
        float s  = pos ? gs_p[j] : gs_n[j];
        float tt = pos ? gt_p[j] : gt_n[j];
        float e = FAST_EXP2(a * u2);
        float y = fmaf(tt, u2, fmaf(s, e, -s));
        as[j] += y;
        aq[j] = fmaf(y, y, aq[j]);
      }
    }
  }

  // merge the two row-subs via LDS; sub0 stores
  if (sub == 1) {
#pragma unroll
    for (int j = 0; j < 6; ++j) { red[j][f] = as[j]; red[6 + j][f] = aq[j]; }
    red[12][f] = u2p; red[13][f] = u2a;
  }
  __syncthreads();
  if (sub == 0) {
#pragma unroll
    for (int j = 0; j < 6; ++j) {
      P1[((size_t)c * 14 + j) * NFEAT + f]     = as[j] + red[j][f];
      P1[((size_t)c * 14 + 6 + j) * NFEAT + f] = aq[j] + red[6 + j][f];
    }
    P1[((size_t)c * 14 + 12) * NFEAT + f] = u2p + red[12][f];
    P1[((size_t)c * 14 + 13) * NFEAT + f] = u2a + red[13][f];
  }
}

// Stage A reduce: block (k, cg): S2[(k*RGRP+cg)*NFEAT+f] = sum over c-subrange.
__global__ __launch_bounds__(256) void k_reduce_S(
    const float* __restrict__ P1, double* __restrict__ S2, int CHv)
{
  const int k = blockIdx.x / RGRP;
  const int cg = blockIdx.x % RGRP;
  const int f = threadIdx.x;
  const int per = CHv / RGRP;
  const int c0 = cg * per;
  double a0 = 0.0, a1 = 0.0, a2 = 0.0, a3 = 0.0;
  for (int c = c0; c < c0 + per; c += 4) {
    a0 += (double)P1[((size_t)(c + 0) * 14 + k) * NFEAT + f];
    a1 += (double)P1[((size_t)(c + 1) * 14 + k) * NFEAT + f];
    a2 += (double)P1[((size_t)(c + 2) * 14 + k) * NFEAT + f];
    a3 += (double)P1[((size_t)(c + 3) * 14 + k) * NFEAT + f];
  }
  S2[((size_t)k * RGRP + cg) * NFEAT + f] = (a0 + a1) + (a2 + a3);
}

// One thread per feature: 6 scores in f64, min, tie-average.
__global__ __launch_bounds__(256) void k_pick(
    const double* __restrict__ S2, const float* __restrict__ lam1,
    const float* __restrict__ lam2, const float* __restrict__ rp,
    float* __restrict__ bestL, int* __restrict__ tied,
    double* __restrict__ bitsF, int* __restrict__ anyTied)
{
  const int f = threadIdx.x;
  if (f == 0) *anyTied = 0;
  double s[14];
#pragma unroll
  for (int k = 0; k < 14; ++k) {
    double a = 0.0;
#pragma unroll
    for (int cg = 0; cg < RGRP; ++cg)
      a += S2[((size_t)k * RGRP + cg) * NFEAT + f];
    s[k] = a;
  }
  const double n = (double)NROWS;
  const double sup = s[12];
  const double sun = s[13] - s[12];
  const float L1 = lam1[f], L2 = lam2[f];
  double scores[6], al1[6], al2[6];
#pragma unroll
  for (int j = 0; j < 6; ++j) {
    float l1 = (j == 0) ? L1 : L1 + 0.1f * rp[f * 10 + 2 * (j - 1)];
    float l2 = (j == 0) ? L2 : L2 + 0.1f * rp[f * 10 + 2 * (j - 1) + 1];
    al1[j] = (double)l1; al2[j] = (double)l2;
    bool z1 = fabsf(l1) < F_EPS;
    bool z2 = fabsf(l2 - 2.0f) < F_EPS;
    double ccp = z1 ? -1.0 : (double)l1 - 1.0;
    double ccn = z2 ? -1.0 : 1.0 - (double)l2;
    double ljb = ccp * sup + ccn * sun;
    double mean = s[j] / n;
    double var = s[6 + j] / n - mean * mean;
    var = var > 1e-12 ? var : 1e-12;
    scores[j] = n * (D_HALF_LOG2_2PIE + 0.5 * log2(var)) + ljb + D_LAMBDA_BITS;
  }
  double mn = scores[0];
#pragma unroll
  for (int j = 1; j < 6; ++j) mn = scores[j] < mn ? scores[j] : mn;
  double wsum = 0.0, b1 = 0.0, b2 = 0.0;
#pragma unroll
  for (int j = 0; j < 6; ++j) {
    double w = (scores[j] == mn) ? 1.0 : 0.0;
    wsum += w; b1 += w * al1[j]; b2 += w * al2[j];
  }
  bestL[2 * f]     = (float)(b1 / wsum);
  bestL[2 * f + 1] = (float)(b2 / wsum);
  const int isTied = (wsum > 1.5) ? 1 : 0;
  tied[f] = isTied;
  if (isTied) atomicOr(anyTied, 1);
  bitsF[f] = mn;   // unique min: identical to re-evaluating at best lambda
}

// Fallback pass 2 (only if some feature tied: averaged lambda is new).
__global__ __launch_bounds__(256) void k_pass2(
    const float* __restrict__ x, const float* __restrict__ bestL,
    const int* __restrict__ anyTied, float* __restrict__ P2)
{
  if (*anyTied == 0) return;
  const int t = threadIdx.x;
  const int c = blockIdx.x;
  const int rpt = NROWS / CH2;   // 128
  const float l1 = bestL[2 * t], l2 = bestL[2 * t + 1];
  const bool z1 = fabsf(l1) < F_EPS;
  const bool z2 = fabsf(l2 - 2.0f) < F_EPS;
  const float tm = 2.0f - l2;
  const float a_p = z1 ? 0.f : l1,  s_pv = z1 ? 0.f : 1.f / l1,  t_pv = z1 ? F_LN2 : 0.f;
  const float a_n = z2 ? 0.f : tm,  s_nv = z2 ? 0.f : -1.f / tm, t_nv = z2 ? -F_LN2 : 0.f;

  float sy = 0.f, sq = 0.f;
  const float* xp = x + (size_t)c * rpt * NFEAT + t;
  for (int i = 0; i < rpt; ++i) {
    float v = xp[(size_t)i * NFEAT];
    bool pos = v >= 0.0f;
    float u2 = FAST_LOG2(1.0f + fabsf(v));
    float a  = pos ? a_p : a_n;
    float s  = pos ? s_pv : s_nv;
    float tt = pos ? t_pv : t_nv;
    float e = FAST_EXP2(a * u2);
    float y = fmaf(tt, u2, fmaf(s, e, -s));
    sy += y;
    sq = fmaf(y, y, sq);
  }
  P2[((size_t)c * 2 + 0) * NFEAT + t] = sy;
  P2[((size_t)c * 2 + 1) * NFEAT + t] = sq;
}

__global__ __launch_bounds__(64) void k_featbits(
    const float* __restrict__ P1, const float* __restrict__ P2,
    const float* __restrict__ bestL, const int* __restrict__ tied,
    double* __restrict__ bitsF, int CHv)
{
  const int f = blockIdx.x;
  if (!tied[f]) return;
  const int lane = threadIdx.x;
  double s0 = 0.0, s1 = 0.0, sup = 0.0, sua = 0.0;
  for (int c = lane; c < CH2; c += 64) {
    s0 += (double)P2[((size_t)c * 2 + 0) * NFEAT + f];
    s1 += (double)P2[((size_t)c * 2 + 1) * NFEAT + f];
  }
  for (int c = lane; c < CHv; c += 64) {
    sup += (double)P1[((size_t)c * 14 + 12) * NFEAT + f];
    sua += (double)P1[((size_t)c * 14 + 13) * NFEAT + f];
  }
  s0 = wave_reduce_add(s0); s1 = wave_reduce_add(s1);
  sup = wave_reduce_add(sup); sua = wave_reduce_add(sua);
  if (lane == 0) {
    const float l1 = bestL[2 * f], l2 = bestL[2 * f + 1];
    bool z1 = fabsf(l1) < F_EPS;
    bool z2 = fabsf(l2 - 2.0f) < F_EPS;
    double ccp = z1 ? -1.0 : (double)l1 - 1.0;
    double ccn = z2 ? -1.0 : 1.0 - (double)l2;
    double ljb = ccp * sup + ccn * (sua - sup);
    const double n = (double)NROWS;
    double mean = s0 / n;
    double var = s1 / n - mean * mean;
    var = var > 1e-12 ? var : 1e-12;
    bitsF[f] = n * (D_HALF_LOG2_2PIE + 0.5 * log2(var)) + ljb + D_LAMBDA_BITS;
  }
}

__global__ __launch_bounds__(256) void k_final(
    const double* __restrict__ bitsF, const double* __restrict__ pSums,
    float* __restrict__ out)
{
  __shared__ double l[4];
  double s = bitsF[threadIdx.x];
  s = wave_reduce_add(s);
  int w = threadIdx.x >> 6;
  if ((threadIdx.x & 63) == 0) l[w] = s;
  __syncthreads();
  if (threadIdx.x == 0) {
    double data = l[0] + l[1] + l[2] + l[3];
    const double n = (double)PCOUNT;
    double mean = pSums[0] / n;
    double var = pSums[1] / n - mean * mean;
    var = var > 1e-12 ? var : 1e-12;
    double model = n * (D_HALF_LOG2_2PIE + 0.5 * log2(var)) + D_LAMBDA_BITS;
    out[0] = (float)(data + model);
  }
}

extern "C" void kernel_launch(void* const* d_in, const int* in_sizes, int n_in,
                              void* d_out, int out_size, void* d_ws, size_t ws_size,
                              hipStream_t stream)
{
  const float* x      = (const float*)d_in[0];
  const float* lam1   = (const float*)d_in[1];
  const float* lam2   = (const float*)d_in[2];
  const float* rp     = (const float*)d_in[3];
  const float* params = (const float*)d_in[4];

  char* ws = (char*)d_ws;
  double* pSums  = (double*)ws;                 // 16 B   -> 16
  float*  bestL  = (float*)(ws + 16);           // 2048   -> 2064
  double* bitsF  = (double*)(ws + 2064);        // 2048   -> 4112
  int*    tied   = (int*)(ws + 4112);           // 1024   -> 5136
  int*    anyT   = (int*)(ws + 5136);           // 4      -> pad 5152
  double* S2     = (double*)(ws + 5152);        // 14*8*256*8 = 229376 -> 234528
  float*  P1     = (float*)(ws + 234528);

  // adaptive chunk count: prefer CH=1024 (2 blocks/CU of 512 threads)
  int CHv = 1024;
  while (CHv > 256) {
    size_t need = 234528 + (size_t)CHv * 14 * NFEAT * 4
                         + (size_t)CH2 * 2 * NFEAT * 4;
    if (need <= ws_size) break;
    CHv >>= 1;
  }
  float* P2 = (float*)(ws + 234528 + (size_t)CHv * 14 * NFEAT * 4);
  int rpt = NROWS / CHv;

  (void)hipMemsetAsync(pSums, 0, 16, stream);
  k_pass1<<<CHv + PBLK, 512, 0, stream>>>(x, lam1, lam2, rp, params, P1,
                                          pSums, CHv, rpt);
  k_reduce_S<<<14 * RGRP, 256, 0, stream>>>(P1, S2, CHv);
  k_pick<<<1, 256, 0, stream>>>(S2, lam1, lam2, rp, bestL, tied, bitsF, anyT);
  k_pass2<<<CH2, 256, 0, stream>>>(x, bestL, anyT, P2);
  k_featbits<<<NFEAT, 64, 0, stream>>>(P1, P2, bestL, tied, bitsF, CHv);
  k_final<<<1, 256, 0, stream>>>(bitsF, pSums, (float*)d_out);
}